// Round 3
// baseline (1056.550 us; speedup 1.0000x reference)
//
#include <hip/hip_runtime.h>

// Problem geometry
// x: (8,96,256,256) fp32. BC = 768 images of 256x256.
// Out 0: xlo (768,128,128)  = 12,582,912 floats
// Out 1: xhi_dir (768,4,128,128) = 50,331,648 floats
// Scratch: xhi staged in the out-1 region; y0/y1 in d_ws.
//
// R1 (third submission; two infra failures, code audited clean): register-
// block all four kernels (multiple outputs/thread) to cut load-issue count
// 2-3.4x. Theory: pipeline was load-issue bound, not HBM bound
// (1141us vs ~230us HBM floor).

#define BC 768

// ---------------------------------------------------------------------------
// K1: xlo[r,c] = sum_{i,j<5} h[i]h[j] x[(2r+i-2)%256, (2c+j-2)%256]
// 2x2 outputs/thread: shared 7x7 input patch (49 loads for 4 outputs vs 100).
// Separable: per patch row compute 2 col-sums (dc=0,1), then row-combine.
// ---------------------------------------------------------------------------
__global__ __launch_bounds__(256) void k1_lowpass(
    const float* __restrict__ x, const float* __restrict__ h,
    float* __restrict__ xlo)
{
    __shared__ float hs[5];
    int t = threadIdx.x;
    if (t < 5) hs[t] = h[t];
    __syncthreads();

    int tid = blockIdx.x * 256 + t;
    int cb = tid & 63;          // output col block (c = 2cb, 2cb+1)
    int rb = (tid >> 6) & 63;   // output row block (r = 2rb, 2rb+1)
    int bc = tid >> 12;
    const float* xb = x + (size_t)bc * 65536;

    int col[7];
    #pragma unroll
    for (int j = 0; j < 7; ++j) col[j] = (4 * cb - 2 + j) & 255;

    float a00 = 0.f, a01 = 0.f, a10 = 0.f, a11 = 0.f;
    #pragma unroll
    for (int pr = 0; pr < 7; ++pr) {
        int row = (4 * rb - 2 + pr) & 255;
        const float* xr = xb + row * 256;
        float X[7];
        #pragma unroll
        for (int j = 0; j < 7; ++j) X[j] = xr[col[j]];
        float s0 = hs[0]*X[0] + hs[1]*X[1] + hs[2]*X[2] + hs[3]*X[3] + hs[4]*X[4];
        float s1 = hs[0]*X[2] + hs[1]*X[3] + hs[2]*X[4] + hs[3]*X[5] + hs[4]*X[6];
        if (pr <= 4) { a00 += hs[pr] * s0;     a01 += hs[pr] * s1; }
        if (pr >= 2) { a10 += hs[pr - 2] * s0; a11 += hs[pr - 2] * s1; }
    }
    size_t ob = (size_t)bc * 16384 + (size_t)(2 * rb) * 128 + 2 * cb;
    *(float2*)(xlo + ob)       = make_float2(a00, a01);
    *(float2*)(xlo + ob + 128) = make_float2(a10, a11);
}

// ---------------------------------------------------------------------------
// K2: xhi[h,w] = x[h,w] - sum g[i]g[j] up[(h+i-3)%256,(w+j-3)%256]
// All 4 polyphase parities per thread: the 4x4 xlo tap window is identical.
// 16 xlo loads + 2 float2 x loads for 4 outputs (vs 68 loads before).
// ---------------------------------------------------------------------------
__global__ __launch_bounds__(256) void k2_highpass(
    const float* __restrict__ x, const float* __restrict__ g,
    const float* __restrict__ xlo, float* __restrict__ xhi)
{
    __shared__ float gs[7];
    int t = threadIdx.x;
    if (t < 7) gs[t] = g[t];
    __syncthreads();

    int tid = blockIdx.x * 256 + t;
    int ch = tid & 127;          // chat: w = 2ch, 2ch+1
    int rh = (tid >> 7) & 127;   // rhat: h = 2rh, 2rh+1
    int bc = tid >> 14;
    const float* lob = xlo + (size_t)bc * 16384;

    int ri[4] = { (rh - 1) & 127, rh, (rh + 1) & 127, (rh + 2) & 127 };
    int ci[4] = { (ch - 1) & 127, ch, (ch + 1) & 127, (ch + 2) & 127 };

    float ce[4], co[4];
    #pragma unroll
    for (int a = 0; a < 4; ++a) {
        const float* lr = lob + ri[a] * 128;
        float L0 = lr[ci[0]], L1 = lr[ci[1]], L2 = lr[ci[2]], L3 = lr[ci[3]];
        ce[a] = gs[1]*L0 + gs[3]*L1 + gs[5]*L2;
        co[a] = gs[0]*L0 + gs[2]*L1 + gs[4]*L2 + gs[6]*L3;
    }
    float aee = gs[1]*ce[0] + gs[3]*ce[1] + gs[5]*ce[2];
    float aeo = gs[1]*co[0] + gs[3]*co[1] + gs[5]*co[2];
    float aoe = gs[0]*ce[0] + gs[2]*ce[1] + gs[4]*ce[2] + gs[6]*ce[3];
    float aoo = gs[0]*co[0] + gs[2]*co[1] + gs[4]*co[2] + gs[6]*co[3];

    size_t base = (size_t)bc * 65536 + (size_t)(2 * rh) * 256 + 2 * ch;
    float2 xe = *(const float2*)(x + base);
    float2 xo = *(const float2*)(x + base + 256);
    *(float2*)(xhi + base)       = make_float2(xe.x - aee, xe.y - aeo);
    *(float2*)(xhi + base + 256) = make_float2(xo.x - aoe, xo.y - aoo);
}

// ---------------------------------------------------------------------------
// K3: y{0,1}[r,w] = sum_{i,j} f{0,1}[i,j] xhi[(2r+i-3)%256, (w+2r+j-3)%256]
// 4 consecutive w outputs/thread: 7x10 window = 70 loads for 4 outputs
// (vs 196). float4 stores.
// ---------------------------------------------------------------------------
__global__ __launch_bounds__(256) void k3_dirfilt(
    const float* __restrict__ xhi, const float* __restrict__ f0,
    const float* __restrict__ f1, float* __restrict__ y0,
    float* __restrict__ y1)
{
    __shared__ float F0[49], F1[49];
    int t = threadIdx.x;
    if (t < 49) F0[t] = f0[t];
    else if (t < 98) F1[t - 49] = f1[t - 49];
    __syncthreads();

    int tid = blockIdx.x * 256 + t;
    int wb = tid & 63;           // w = 4wb .. 4wb+3
    int r  = (tid >> 6) & 127;
    int bc = tid >> 13;
    const float* xb = xhi + (size_t)bc * 65536;

    int colbase = 4 * wb + 2 * r - 3 + 256;
    int col[10];
    #pragma unroll
    for (int m = 0; m < 10; ++m) col[m] = (colbase + m) & 255;

    float a0[4] = {0.f, 0.f, 0.f, 0.f};
    float a1[4] = {0.f, 0.f, 0.f, 0.f};
    #pragma unroll
    for (int i = 0; i < 7; ++i) {
        int row = (2 * r + i - 3 + 256) & 255;
        const float* xr = xb + row * 256;
        float C[10];
        #pragma unroll
        for (int m = 0; m < 10; ++m) C[m] = xr[col[m]];
        #pragma unroll
        for (int j = 0; j < 7; ++j) {
            float f0v = F0[i * 7 + j];
            float f1v = F1[i * 7 + j];
            #pragma unroll
            for (int d = 0; d < 4; ++d) {
                a0[d] += f0v * C[d + j];
                a1[d] += f1v * C[d + j];
            }
        }
    }
    size_t o = (size_t)bc * 32768 + (size_t)r * 256 + 4 * wb;
    *(float4*)(y0 + o) = make_float4(a0[0], a0[1], a0[2], a0[3]);
    *(float4*)(y1 + o) = make_float4(a1[0], a1[1], a1[2], a1[3]);
}

// ---------------------------------------------------------------------------
// K4: out[d, hh, cc] = sum_{i,j} fT[i,j] y[(hh+2cc+i-3)%128, (2cc+j-3)%256]
// fT[i][j] = f[j][i]. LDS tile 100x70 (pad 80). Thread's 4 outputs are
// CONSECUTIVE dhh (4*lh+k): sliding 10x7 window = 70 ds_reads for 4 outputs
// (vs 196 at dhh=lh+8k).
// ---------------------------------------------------------------------------
#define TH 32
#define TC 32
#define NR (TH + 2 * TC + 4)   // 100
#define NC (2 * TC + 6)        // 70
#define NCP 80

__global__ __launch_bounds__(256) void k4_qdc(
    const float* __restrict__ ybuf, const float* __restrict__ f0,
    const float* __restrict__ f1, float* __restrict__ out_hi)
{
    __shared__ float tile[NR * NCP];
    __shared__ float F0[49], F1[49];
    int t = threadIdx.x;
    if (t < 49) F0[t] = f0[t];
    else if (t < 98) F1[t - 49] = f1[t - 49];

    int bx   = blockIdx.x;
    int ccb  = (bx & 3) * TC;
    int hhb  = ((bx >> 2) & 3) * TH;
    int yidx = (bx >> 4) & 1;
    int bc   = bx >> 5;
    const float* yb = ybuf + ((size_t)yidx * BC + bc) * 32768;

    int r0 = (hhb + 2 * ccb - 3 + 128) & 127;
    int c0 = (2 * ccb - 3 + 256) & 255;

    for (int idx = t; idx < NR * NC; idx += 256) {
        int rr = idx / NC;
        int cc = idx - rr * NC;
        int gr = (r0 + rr) & 127;
        int gc = (c0 + cc) & 255;
        tile[rr * NCP + cc] = yb[gr * 256 + gc];
    }
    __syncthreads();

    int lc = t & 31;        // delta cc
    int lh = t >> 5;        // 0..7 -> dhh = 4*lh + k
    int cc = ccb + lc;
    int cbase = 2 * lc;
    int rbase0 = 4 * lh + 2 * lc;   // max 28+62+9 = 99 < NR

    float s0[4] = {0.f, 0.f, 0.f, 0.f};
    float s1[4] = {0.f, 0.f, 0.f, 0.f};
    #pragma unroll
    for (int RR = 0; RR < 10; ++RR) {
        const float* tr = &tile[(rbase0 + RR) * NCP + cbase];
        float T[7];
        #pragma unroll
        for (int j = 0; j < 7; ++j) T[j] = tr[j];
        #pragma unroll
        for (int k = 0; k < 4; ++k) {
            int i = RR - k;
            if (i >= 0 && i <= 6) {
                #pragma unroll
                for (int j = 0; j < 7; ++j) {
                    s0[k] += F0[j * 7 + i] * T[j];   // f0.T
                    s1[k] += F1[j * 7 + i] * T[j];   // f1.T
                }
            }
        }
    }
    #pragma unroll
    for (int k = 0; k < 4; ++k) {
        int hh = hhb + 4 * lh + k;
        size_t o = (size_t)bc * 65536 + (size_t)(2 * yidx) * 16384
                 + (size_t)hh * 128 + cc;
        out_hi[o]         = s0[k];
        out_hi[o + 16384] = s1[k];
    }
}

// ---------------------------------------------------------------------------
extern "C" void kernel_launch(void* const* d_in, const int* in_sizes, int n_in,
                              void* d_out, int out_size, void* d_ws, size_t ws_size,
                              hipStream_t stream)
{
    const float* x  = (const float*)d_in[0];
    const float* h  = (const float*)d_in[1];
    const float* g  = (const float*)d_in[2];
    const float* f0 = (const float*)d_in[3];
    const float* f1 = (const float*)d_in[4];

    float* out   = (float*)d_out;
    float* xlo   = out;                 // 768*16384 floats
    float* hireg = out + 12582912;      // 768*65536 floats: xhi scratch, then final
    float* ybuf  = (float*)d_ws;        // y0 then y1, each 768*32768 floats

    k1_lowpass<<<12288, 256, 0, stream>>>(x, h, xlo);
    k2_highpass<<<49152, 256, 0, stream>>>(x, g, xlo, hireg);
    k3_dirfilt<<<24576, 256, 0, stream>>>(hireg, f0, f1, ybuf, ybuf + 25165824);
    k4_qdc<<<24576, 256, 0, stream>>>(ybuf, f0, f1, hireg);
}

// Round 4
// 813.476 us; speedup vs baseline: 1.2988x; 1.2988x over previous
//
#include <hip/hip_runtime.h>

// Problem geometry
// x: (8,96,256,256) fp32. BC = 768 images of 256x256.
// Out 0: xlo (768,128,128); Out 1: xhi_dir (768,4,128,128).
// Scratch: SHEARED xhi (xs) staged in the out-1 region; y0/y1 in d_ws.
//
// R4: K3 was 401us at 11% HBM / 17% VALU => VMEM address-pipe bound
// (16B-lane-stride scalar loads, ~36cyc/wave-load measured). Fix: store xhi
// PRE-SHEARED in K2: xs[row][(col-row+2)%256] = xhi[row][col]. K3's read col
// becomes w+(j-i)+2, row-independent => aligned float4 coalesced loads, no
// LDS. Also: K1 scalar->float2 loads, K4 LDS b32(4-way conflict)->b64 contig.

#define BC 768

// ---------------------------------------------------------------------------
// K1: xlo[r,c] = sum_{i,j<5} h[i]h[j] x[(2r+i-2)%256, (2c+j-2)%256]
// 2x2 outputs/thread, 7x7 patch via 4 float2 loads/row (28 b64 vs 49 b32).
// ---------------------------------------------------------------------------
__global__ __launch_bounds__(256) void k1_lowpass(
    const float* __restrict__ x, const float* __restrict__ h,
    float* __restrict__ xlo)
{
    __shared__ float hs[5];
    int t = threadIdx.x;
    if (t < 5) hs[t] = h[t];
    __syncthreads();

    int tid = blockIdx.x * 256 + t;
    int cb = tid & 63;          // output cols 2cb, 2cb+1
    int rb = (tid >> 6) & 63;   // output rows 2rb, 2rb+1
    int bc = tid >> 12;
    const float* xb = x + (size_t)bc * 65536;

    int colp[4];                // even base 4cb-2+2k, pairs never wrap
    #pragma unroll
    for (int k = 0; k < 4; ++k) colp[k] = (4 * cb - 2 + 2 * k) & 255;

    float a00 = 0.f, a01 = 0.f, a10 = 0.f, a11 = 0.f;
    #pragma unroll
    for (int pr = 0; pr < 7; ++pr) {
        int row = (4 * rb - 2 + pr) & 255;
        const float* xr = xb + row * 256;
        float X[8];
        #pragma unroll
        for (int k = 0; k < 4; ++k) {
            float2 p = *(const float2*)(xr + colp[k]);
            X[2 * k] = p.x; X[2 * k + 1] = p.y;
        }
        float s0 = hs[0]*X[0] + hs[1]*X[1] + hs[2]*X[2] + hs[3]*X[3] + hs[4]*X[4];
        float s1 = hs[0]*X[2] + hs[1]*X[3] + hs[2]*X[4] + hs[3]*X[5] + hs[4]*X[6];
        if (pr <= 4) { a00 += hs[pr] * s0;     a01 += hs[pr] * s1; }
        if (pr >= 2) { a10 += hs[pr - 2] * s0; a11 += hs[pr - 2] * s1; }
    }
    size_t ob = (size_t)bc * 16384 + (size_t)(2 * rb) * 128 + 2 * cb;
    *(float2*)(xlo + ob)       = make_float2(a00, a01);
    *(float2*)(xlo + ob + 128) = make_float2(a10, a11);
}

// ---------------------------------------------------------------------------
// K2: xhi[h,w] = x[h,w] - sum g[i]g[j] up[(h+i-3)%256,(w+j-3)%256]
// 4 polyphase parities/thread (shared 4x4 xlo window). Output stored SHEARED:
// xs[row][(col-row+2)&255] = xhi[row][col].
// Even rows: col' even -> float2 store. Odd rows: col' odd -> 2 b32 stores.
// ---------------------------------------------------------------------------
__global__ __launch_bounds__(256) void k2_highpass(
    const float* __restrict__ x, const float* __restrict__ g,
    const float* __restrict__ xlo, float* __restrict__ xs)
{
    __shared__ float gs[7];
    int t = threadIdx.x;
    if (t < 7) gs[t] = g[t];
    __syncthreads();

    int tid = blockIdx.x * 256 + t;
    int ch = tid & 127;          // w = 2ch, 2ch+1
    int rh = (tid >> 7) & 127;   // h = 2rh, 2rh+1
    int bc = tid >> 14;
    const float* lob = xlo + (size_t)bc * 16384;

    int ri[4] = { (rh - 1) & 127, rh, (rh + 1) & 127, (rh + 2) & 127 };
    int ci[4] = { (ch - 1) & 127, ch, (ch + 1) & 127, (ch + 2) & 127 };

    float ce[4], co[4];
    #pragma unroll
    for (int a = 0; a < 4; ++a) {
        const float* lr = lob + ri[a] * 128;
        float L0 = lr[ci[0]], L1 = lr[ci[1]], L2 = lr[ci[2]], L3 = lr[ci[3]];
        ce[a] = gs[1]*L0 + gs[3]*L1 + gs[5]*L2;
        co[a] = gs[0]*L0 + gs[2]*L1 + gs[4]*L2 + gs[6]*L3;
    }
    float aee = gs[1]*ce[0] + gs[3]*ce[1] + gs[5]*ce[2];
    float aeo = gs[1]*co[0] + gs[3]*co[1] + gs[5]*co[2];
    float aoe = gs[0]*ce[0] + gs[2]*ce[1] + gs[4]*ce[2] + gs[6]*ce[3];
    float aoo = gs[0]*co[0] + gs[2]*co[1] + gs[4]*co[2] + gs[6]*co[3];

    size_t base = (size_t)bc * 65536 + (size_t)(2 * rh) * 256 + 2 * ch;
    float2 xe = *(const float2*)(x + base);
    float2 xo = *(const float2*)(x + base + 256);

    float* xsb = (float*)xs + (size_t)bc * 65536;
    int re = 2 * rh, ro = 2 * rh + 1;
    int ce0 = (2 * ch - re + 2) & 255;              // even
    int co0 = (2 * ch - ro + 2) & 255;              // odd
    *(float2*)(xsb + re * 256 + ce0) = make_float2(xe.x - aee, xe.y - aeo);
    float* rowo = xsb + ro * 256;
    rowo[co0]             = xo.x - aoe;
    rowo[(co0 + 1) & 255] = xo.y - aoo;
}

// ---------------------------------------------------------------------------
// K3: y{0,1}[r,w] = sum_{i,j} f{0,1}[i,j] xhi[(2r+i-3)%256, (w+2r+j-3)%256]
// Sheared read: xs[row][(w + j - i + 2)&255] == xhi[row][w+2r+j-3] for
// row = 2r+i-3. Column window is ROW-INDEPENDENT: 16 floats from 4wb-4
// (0 mod 4 => aligned float4). Thread: 4 w x 2 output rows, 9 input rows,
// 36 b128 coalesced loads + 784 FMA per 8 outputs x 2 filters. No LDS tile.
// ---------------------------------------------------------------------------
__global__ __launch_bounds__(256) void k3_dirfilt(
    const float* __restrict__ xs, const float* __restrict__ f0,
    const float* __restrict__ f1, float* __restrict__ y0,
    float* __restrict__ y1)
{
    __shared__ float F0[49], F1[49];
    int t = threadIdx.x;
    if (t < 49) F0[t] = f0[t];
    else if (t < 98) F1[t - 49] = f1[t - 49];
    __syncthreads();

    int wb = t & 63;            // w = 4wb .. 4wb+3
    int rg = t >> 6;            // 0..3 -> output rows r0+2rg, r0+2rg+1
    int r0 = (blockIdx.x & 15) * 8;
    int bc = blockIdx.x >> 4;
    const float* xsb = xs + (size_t)bc * 65536;

    int base = 2 * r0 + 4 * rg - 3;     // first input row
    int c0 = (4 * wb - 4) & 255;        // aligned, 256%4==0 => no intra-vec wrap

    float a0[2][4] = {{0.f,0.f,0.f,0.f},{0.f,0.f,0.f,0.f}};
    float a1[2][4] = {{0.f,0.f,0.f,0.f},{0.f,0.f,0.f,0.f}};

    #pragma unroll
    for (int ro = 0; ro < 9; ++ro) {
        int row = (base + ro) & 255;
        const float* rp = xsb + row * 256;
        float C[16];
        #pragma unroll
        for (int k = 0; k < 4; ++k) {
            float4 v = *(const float4*)(rp + ((c0 + 4 * k) & 255));
            C[4*k] = v.x; C[4*k+1] = v.y; C[4*k+2] = v.z; C[4*k+3] = v.w;
        }
        #pragma unroll
        for (int lr = 0; lr < 2; ++lr) {
            int i = ro - 2 * lr;
            if (i >= 0 && i <= 6) {
                #pragma unroll
                for (int j = 0; j < 7; ++j) {
                    float w0 = F0[i * 7 + j];
                    float w1 = F1[i * 7 + j];
                    int mb = j - ro + 2 * lr + 6;   // m = dw + mb
                    #pragma unroll
                    for (int dw = 0; dw < 4; ++dw) {
                        float v = C[dw + mb];
                        a0[lr][dw] += w0 * v;
                        a1[lr][dw] += w1 * v;
                    }
                }
            }
        }
    }
    #pragma unroll
    for (int lr = 0; lr < 2; ++lr) {
        int r = r0 + 2 * rg + lr;
        size_t o = (size_t)bc * 32768 + (size_t)r * 256 + 4 * wb;
        *(float4*)(y0 + o) = make_float4(a0[lr][0], a0[lr][1], a0[lr][2], a0[lr][3]);
        *(float4*)(y1 + o) = make_float4(a1[lr][0], a1[lr][1], a1[lr][2], a1[lr][3]);
    }
}

// ---------------------------------------------------------------------------
// K4: out[d, hh, cc] = sum_{i,j} fT[i,j] y[(hh+2cc+i-3)%128, (2cc+j-3)%256]
// LDS tile 100x70 (pad 80). 4 consecutive dhh/thread (sliding 10x7 window).
// Tile row reads via 4 contiguous float2 (b64) instead of 7 b32 at 8B stride
// (which was a 4-way bank conflict).
// ---------------------------------------------------------------------------
#define TH 32
#define TC 32
#define NR (TH + 2 * TC + 4)   // 100
#define NC (2 * TC + 6)        // 70
#define NCP 80

__global__ __launch_bounds__(256) void k4_qdc(
    const float* __restrict__ ybuf, const float* __restrict__ f0,
    const float* __restrict__ f1, float* __restrict__ out_hi)
{
    __shared__ float tile[NR * NCP];
    __shared__ float F0[49], F1[49];
    int t = threadIdx.x;
    if (t < 49) F0[t] = f0[t];
    else if (t < 98) F1[t - 49] = f1[t - 49];

    int bx   = blockIdx.x;
    int ccb  = (bx & 3) * TC;
    int hhb  = ((bx >> 2) & 3) * TH;
    int yidx = (bx >> 4) & 1;
    int bc   = bx >> 5;
    const float* yb = ybuf + ((size_t)yidx * BC + bc) * 32768;

    int r0 = (hhb + 2 * ccb - 3 + 128) & 127;
    int c0 = (2 * ccb - 3 + 256) & 255;

    for (int idx = t; idx < NR * NC; idx += 256) {
        int rr = idx / NC;
        int cc = idx - rr * NC;
        int gr = (r0 + rr) & 127;
        int gc = (c0 + cc) & 255;
        tile[rr * NCP + cc] = yb[gr * 256 + gc];
    }
    __syncthreads();

    int lc = t & 31;
    int lh = t >> 5;             // dhh = 4*lh + k
    int cc = ccb + lc;
    int cbase = 2 * lc;          // even -> b64-aligned
    int rbase0 = 4 * lh + 2 * lc;

    float s0[4] = {0.f, 0.f, 0.f, 0.f};
    float s1[4] = {0.f, 0.f, 0.f, 0.f};
    #pragma unroll
    for (int RR = 0; RR < 10; ++RR) {
        const float* tr = &tile[(rbase0 + RR) * NCP + cbase];
        float T[8];
        #pragma unroll
        for (int k = 0; k < 4; ++k) {
            float2 u = *(const float2*)(tr + 2 * k);
            T[2*k] = u.x; T[2*k+1] = u.y;
        }
        #pragma unroll
        for (int k = 0; k < 4; ++k) {
            int i = RR - k;
            if (i >= 0 && i <= 6) {
                #pragma unroll
                for (int j = 0; j < 7; ++j) {
                    s0[k] += F0[j * 7 + i] * T[j];   // f0.T
                    s1[k] += F1[j * 7 + i] * T[j];   // f1.T
                }
            }
        }
    }
    #pragma unroll
    for (int k = 0; k < 4; ++k) {
        int hh = hhb + 4 * lh + k;
        size_t o = (size_t)bc * 65536 + (size_t)(2 * yidx) * 16384
                 + (size_t)hh * 128 + cc;
        out_hi[o]         = s0[k];
        out_hi[o + 16384] = s1[k];
    }
}

// ---------------------------------------------------------------------------
extern "C" void kernel_launch(void* const* d_in, const int* in_sizes, int n_in,
                              void* d_out, int out_size, void* d_ws, size_t ws_size,
                              hipStream_t stream)
{
    const float* x  = (const float*)d_in[0];
    const float* h  = (const float*)d_in[1];
    const float* g  = (const float*)d_in[2];
    const float* f0 = (const float*)d_in[3];
    const float* f1 = (const float*)d_in[4];

    float* out   = (float*)d_out;
    float* xlo   = out;                 // 768*16384 floats
    float* hireg = out + 12582912;      // 768*65536: sheared xhi, then final
    float* ybuf  = (float*)d_ws;        // y0 then y1, each 768*32768 floats

    k1_lowpass<<<12288, 256, 0, stream>>>(x, h, xlo);
    k2_highpass<<<49152, 256, 0, stream>>>(x, g, xlo, hireg);
    k3_dirfilt<<<12288, 256, 0, stream>>>(hireg, f0, f1, ybuf, ybuf + 25165824);
    k4_qdc<<<24576, 256, 0, stream>>>(ybuf, f0, f1, hireg);
}

// Round 5
// 716.200 us; speedup vs baseline: 1.4752x; 1.1358x over previous
//
#include <hip/hip_runtime.h>

// Problem geometry
// x: (8,96,256,256) fp32. BC = 768 images of 256x256.
// Out 0: xlo (768,128,128); Out 1: xhi_dir (768,4,128,128).
// Scratch: SHEARED xhi (xs) in the out-1 region; y0/y1 in d_ws.
//
// R5: K4 was 246us. Diagnosis: ~1:1 filter-LDS-read : FMA ratio (392 LDS
// reads per 8 outputs) => LDS-pipe issue bound, plus 2x tile-halo overfetch
// (FETCH 393MB vs 201 ideal). Fixes:
//  (a) ALL kernels: filters read from global pointers with uniform indices
//      -> s_load to SGPRs (scalar pipe), no __shared__ filter arrays.
//  (b) K4: full-column tile TH=128 (rows mod 128 => zero duplication),
//      32 outputs/thread; FETCH -> ~225MB, tile-reads/output halved.

#define BC 768

// ---------------------------------------------------------------------------
// K1: xlo[r,c] = sum_{i,j<5} h[i]h[j] x[(2r+i-2)%256, (2c+j-2)%256]
// 2x2 outputs/thread, float2 loads; h in SGPRs via uniform global reads.
// ---------------------------------------------------------------------------
__global__ __launch_bounds__(256) void k1_lowpass(
    const float* __restrict__ x, const float* __restrict__ h,
    float* __restrict__ xlo)
{
    int t = threadIdx.x;
    int tid = blockIdx.x * 256 + t;
    int cb = tid & 63;          // output cols 2cb, 2cb+1
    int rb = (tid >> 6) & 63;   // output rows 2rb, 2rb+1
    int bc = tid >> 12;
    const float* xb = x + (size_t)bc * 65536;

    int colp[4];
    #pragma unroll
    for (int k = 0; k < 4; ++k) colp[k] = (4 * cb - 2 + 2 * k) & 255;

    float a00 = 0.f, a01 = 0.f, a10 = 0.f, a11 = 0.f;
    #pragma unroll
    for (int pr = 0; pr < 7; ++pr) {
        int row = (4 * rb - 2 + pr) & 255;
        const float* xr = xb + row * 256;
        float X[8];
        #pragma unroll
        for (int k = 0; k < 4; ++k) {
            float2 p = *(const float2*)(xr + colp[k]);
            X[2 * k] = p.x; X[2 * k + 1] = p.y;
        }
        float s0 = h[0]*X[0] + h[1]*X[1] + h[2]*X[2] + h[3]*X[3] + h[4]*X[4];
        float s1 = h[0]*X[2] + h[1]*X[3] + h[2]*X[4] + h[3]*X[5] + h[4]*X[6];
        if (pr <= 4) { a00 += h[pr] * s0;     a01 += h[pr] * s1; }
        if (pr >= 2) { a10 += h[pr - 2] * s0; a11 += h[pr - 2] * s1; }
    }
    size_t ob = (size_t)bc * 16384 + (size_t)(2 * rb) * 128 + 2 * cb;
    *(float2*)(xlo + ob)       = make_float2(a00, a01);
    *(float2*)(xlo + ob + 128) = make_float2(a10, a11);
}

// ---------------------------------------------------------------------------
// K2: xhi[h,w] = x[h,w] - sum g[i]g[j] up[(h+i-3)%256,(w+j-3)%256]
// 4 polyphase parities/thread. Output stored SHEARED:
// xs[row][(col-row+2)&255] = xhi[row][col]. g in SGPRs.
// ---------------------------------------------------------------------------
__global__ __launch_bounds__(256) void k2_highpass(
    const float* __restrict__ x, const float* __restrict__ g,
    const float* __restrict__ xlo, float* __restrict__ xs)
{
    int t = threadIdx.x;
    int tid = blockIdx.x * 256 + t;
    int ch = tid & 127;          // w = 2ch, 2ch+1
    int rh = (tid >> 7) & 127;   // h = 2rh, 2rh+1
    int bc = tid >> 14;
    const float* lob = xlo + (size_t)bc * 16384;

    int ri[4] = { (rh - 1) & 127, rh, (rh + 1) & 127, (rh + 2) & 127 };
    int ci[4] = { (ch - 1) & 127, ch, (ch + 1) & 127, (ch + 2) & 127 };

    float ce[4], co[4];
    #pragma unroll
    for (int a = 0; a < 4; ++a) {
        const float* lr = lob + ri[a] * 128;
        float L0 = lr[ci[0]], L1 = lr[ci[1]], L2 = lr[ci[2]], L3 = lr[ci[3]];
        ce[a] = g[1]*L0 + g[3]*L1 + g[5]*L2;
        co[a] = g[0]*L0 + g[2]*L1 + g[4]*L2 + g[6]*L3;
    }
    float aee = g[1]*ce[0] + g[3]*ce[1] + g[5]*ce[2];
    float aeo = g[1]*co[0] + g[3]*co[1] + g[5]*co[2];
    float aoe = g[0]*ce[0] + g[2]*ce[1] + g[4]*ce[2] + g[6]*ce[3];
    float aoo = g[0]*co[0] + g[2]*co[1] + g[4]*co[2] + g[6]*co[3];

    size_t base = (size_t)bc * 65536 + (size_t)(2 * rh) * 256 + 2 * ch;
    float2 xe = *(const float2*)(x + base);
    float2 xo = *(const float2*)(x + base + 256);

    float* xsb = xs + (size_t)bc * 65536;
    int re = 2 * rh, ro = 2 * rh + 1;
    int ce0 = (2 * ch - re + 2) & 255;
    int co0 = (2 * ch - ro + 2) & 255;
    *(float2*)(xsb + re * 256 + ce0) = make_float2(xe.x - aee, xe.y - aeo);
    float* rowo = xsb + ro * 256;
    rowo[co0]             = xo.x - aoe;
    rowo[(co0 + 1) & 255] = xo.y - aoo;
}

// ---------------------------------------------------------------------------
// K3: y{0,1}[r,w] = sum_{i,j} f{0,1}[i,j] xhi[(2r+i-3)%256, (w+2r+j-3)%256]
// Sheared read: col window row-independent, aligned float4. Filters in SGPRs.
// Thread: 4 w x 2 rows; 36 b128 loads + 784 FMA per 16 output values.
// ---------------------------------------------------------------------------
__global__ __launch_bounds__(256) void k3_dirfilt(
    const float* __restrict__ xs, const float* __restrict__ f0,
    const float* __restrict__ f1, float* __restrict__ y0,
    float* __restrict__ y1)
{
    int t = threadIdx.x;
    int wb = t & 63;            // w = 4wb .. 4wb+3
    int rg = t >> 6;            // 0..3
    int r0 = (blockIdx.x & 15) * 8;
    int bc = blockIdx.x >> 4;
    const float* xsb = xs + (size_t)bc * 65536;

    int base = 2 * r0 + 4 * rg - 3;
    int c0 = (4 * wb - 4) & 255;

    float a0[2][4] = {{0.f,0.f,0.f,0.f},{0.f,0.f,0.f,0.f}};
    float a1[2][4] = {{0.f,0.f,0.f,0.f},{0.f,0.f,0.f,0.f}};

    #pragma unroll
    for (int ro = 0; ro < 9; ++ro) {
        int row = (base + ro) & 255;
        const float* rp = xsb + row * 256;
        float C[16];
        #pragma unroll
        for (int k = 0; k < 4; ++k) {
            float4 v = *(const float4*)(rp + ((c0 + 4 * k) & 255));
            C[4*k] = v.x; C[4*k+1] = v.y; C[4*k+2] = v.z; C[4*k+3] = v.w;
        }
        #pragma unroll
        for (int lr = 0; lr < 2; ++lr) {
            int i = ro - 2 * lr;
            if (i >= 0 && i <= 6) {
                #pragma unroll
                for (int j = 0; j < 7; ++j) {
                    float w0 = f0[i * 7 + j];
                    float w1 = f1[i * 7 + j];
                    int mb = j - ro + 2 * lr + 6;
                    #pragma unroll
                    for (int dw = 0; dw < 4; ++dw) {
                        float v = C[dw + mb];
                        a0[lr][dw] += w0 * v;
                        a1[lr][dw] += w1 * v;
                    }
                }
            }
        }
    }
    #pragma unroll
    for (int lr = 0; lr < 2; ++lr) {
        int r = r0 + 2 * rg + lr;
        size_t o = (size_t)bc * 32768 + (size_t)r * 256 + 4 * wb;
        *(float4*)(y0 + o) = make_float4(a0[lr][0], a0[lr][1], a0[lr][2], a0[lr][3]);
        *(float4*)(y1 + o) = make_float4(a1[lr][0], a1[lr][1], a1[lr][2], a1[lr][3]);
    }
}

// ---------------------------------------------------------------------------
// K4: out[d, hh, cc] = sum_{i,j} fT[i,j] y[(hh+2cc+i-3)%128, (2cc+j-3)%256]
// Full-column tile: 128 rows x 70 cols (all rows used mod 128 => zero
// duplication; FETCH 393->~225MB). Thread: 16 consecutive hh x 1 cc x 2
// filters = 32 outputs; sliding 22-row window, 88 b64 tile reads. Filters
// from global (SGPR); no filter LDS traffic.
// ---------------------------------------------------------------------------
#define NCP 80   // 70 padded

__global__ __launch_bounds__(256) void k4_qdc(
    const float* __restrict__ ybuf, const float* __restrict__ f0,
    const float* __restrict__ f1, float* __restrict__ out_hi)
{
    __shared__ float tile[128 * NCP];
    int t = threadIdx.x;

    int bx   = blockIdx.x;
    int ccb  = (bx & 3) * 32;
    int yidx = (bx >> 2) & 1;
    int bc   = bx >> 3;
    const float* yb = ybuf + ((size_t)yidx * BC + bc) * 32768;

    int c0 = (2 * ccb - 3 + 256) & 255;

    for (int idx = t; idx < 128 * 70; idx += 256) {
        int rr = idx / 70;
        int cc = idx - rr * 70;
        tile[rr * NCP + cc] = yb[rr * 256 + ((c0 + cc) & 255)];
    }
    __syncthreads();

    int lc = t & 31;
    int lh = t >> 5;                 // hh = 16*lh + m
    int cc = ccb + lc;
    int cbase = 2 * lc;              // tile col of j=0 (0..62, even)
    int rbase = (16 * lh + 2 * cc - 3 + 128) & 127;

    float s0[16], s1[16];
    #pragma unroll
    for (int m = 0; m < 16; ++m) { s0[m] = 0.f; s1[m] = 0.f; }

    #pragma unroll
    for (int RR = 0; RR < 22; ++RR) {
        const float* tr = &tile[((rbase + RR) & 127) * NCP + cbase];
        float T[8];
        #pragma unroll
        for (int k = 0; k < 4; ++k) {
            float2 u = *(const float2*)(tr + 2 * k);
            T[2*k] = u.x; T[2*k+1] = u.y;
        }
        #pragma unroll
        for (int m = 0; m < 16; ++m) {
            int i = RR - m;
            if (i >= 0 && i <= 6) {
                #pragma unroll
                for (int j = 0; j < 7; ++j) {
                    s0[m] += f0[j * 7 + i] * T[j];   // f0.T
                    s1[m] += f1[j * 7 + i] * T[j];   // f1.T
                }
            }
        }
    }
    #pragma unroll
    for (int m = 0; m < 16; ++m) {
        int hh = 16 * lh + m;
        size_t o = (size_t)bc * 65536 + (size_t)(2 * yidx) * 16384
                 + (size_t)hh * 128 + cc;
        out_hi[o]         = s0[m];
        out_hi[o + 16384] = s1[m];
    }
}

// ---------------------------------------------------------------------------
extern "C" void kernel_launch(void* const* d_in, const int* in_sizes, int n_in,
                              void* d_out, int out_size, void* d_ws, size_t ws_size,
                              hipStream_t stream)
{
    const float* x  = (const float*)d_in[0];
    const float* h  = (const float*)d_in[1];
    const float* g  = (const float*)d_in[2];
    const float* f0 = (const float*)d_in[3];
    const float* f1 = (const float*)d_in[4];

    float* out   = (float*)d_out;
    float* xlo   = out;                 // 768*16384 floats
    float* hireg = out + 12582912;      // 768*65536: sheared xhi, then final
    float* ybuf  = (float*)d_ws;        // y0 then y1, each 768*32768 floats

    k1_lowpass<<<12288, 256, 0, stream>>>(x, h, xlo);
    k2_highpass<<<49152, 256, 0, stream>>>(x, g, xlo, hireg);
    k3_dirfilt<<<12288, 256, 0, stream>>>(hireg, f0, f1, ybuf, ybuf + 25165824);
    k4_qdc<<<6144, 256, 0, stream>>>(ybuf, f0, f1, hireg);
}

// Round 6
// 670.409 us; speedup vs baseline: 1.5760x; 1.0683x over previous
//
#include <hip/hip_runtime.h>

// Problem geometry
// x: (8,96,256,256) fp32. BC = 768 images of 256x256.
// Out 0: xlo (768,128,128); Out 1: xhi_dir (768,4,128,128).
// Scratch: SHEARED xhi (xs) now in d_ws (201MB); ybuf ELIMINATED (fused).
//
// R6: fuse K3+K4. Block=(bc,yidx): K3-stage computes full y image (128x256
// = 128KB LDS, 1 block/CU, 1024 thr) from sheared xs; K4-stage computes both
// fT subbands from LDS. Kills the 384MB y-write + ~225-390MB y-read.
// xs moved to d_ws to avoid fused in-place race with the out-1 region.

#define BC 768

// ---------------------------------------------------------------------------
// K1: xlo[r,c] = sum_{i,j<5} h[i]h[j] x[(2r+i-2)%256, (2c+j-2)%256]
// 2x2 outputs/thread, float2 loads; h in SGPRs via uniform global reads.
// ---------------------------------------------------------------------------
__global__ __launch_bounds__(256) void k1_lowpass(
    const float* __restrict__ x, const float* __restrict__ h,
    float* __restrict__ xlo)
{
    int t = threadIdx.x;
    int tid = blockIdx.x * 256 + t;
    int cb = tid & 63;
    int rb = (tid >> 6) & 63;
    int bc = tid >> 12;
    const float* xb = x + (size_t)bc * 65536;

    int colp[4];
    #pragma unroll
    for (int k = 0; k < 4; ++k) colp[k] = (4 * cb - 2 + 2 * k) & 255;

    float a00 = 0.f, a01 = 0.f, a10 = 0.f, a11 = 0.f;
    #pragma unroll
    for (int pr = 0; pr < 7; ++pr) {
        int row = (4 * rb - 2 + pr) & 255;
        const float* xr = xb + row * 256;
        float X[8];
        #pragma unroll
        for (int k = 0; k < 4; ++k) {
            float2 p = *(const float2*)(xr + colp[k]);
            X[2 * k] = p.x; X[2 * k + 1] = p.y;
        }
        float s0 = h[0]*X[0] + h[1]*X[1] + h[2]*X[2] + h[3]*X[3] + h[4]*X[4];
        float s1 = h[0]*X[2] + h[1]*X[3] + h[2]*X[4] + h[3]*X[5] + h[4]*X[6];
        if (pr <= 4) { a00 += h[pr] * s0;     a01 += h[pr] * s1; }
        if (pr >= 2) { a10 += h[pr - 2] * s0; a11 += h[pr - 2] * s1; }
    }
    size_t ob = (size_t)bc * 16384 + (size_t)(2 * rb) * 128 + 2 * cb;
    *(float2*)(xlo + ob)       = make_float2(a00, a01);
    *(float2*)(xlo + ob + 128) = make_float2(a10, a11);
}

// ---------------------------------------------------------------------------
// K2: xhi[h,w] = x[h,w] - sum g[i]g[j] up[(h+i-3)%256,(w+j-3)%256]
// 4 polyphase parities/thread. Output stored SHEARED into d_ws:
// xs[row][(col-row+2)&255] = xhi[row][col]. g in SGPRs.
// ---------------------------------------------------------------------------
__global__ __launch_bounds__(256) void k2_highpass(
    const float* __restrict__ x, const float* __restrict__ g,
    const float* __restrict__ xlo, float* __restrict__ xs)
{
    int t = threadIdx.x;
    int tid = blockIdx.x * 256 + t;
    int ch = tid & 127;
    int rh = (tid >> 7) & 127;
    int bc = tid >> 14;
    const float* lob = xlo + (size_t)bc * 16384;

    int ri[4] = { (rh - 1) & 127, rh, (rh + 1) & 127, (rh + 2) & 127 };
    int ci[4] = { (ch - 1) & 127, ch, (ch + 1) & 127, (ch + 2) & 127 };

    float ce[4], co[4];
    #pragma unroll
    for (int a = 0; a < 4; ++a) {
        const float* lr = lob + ri[a] * 128;
        float L0 = lr[ci[0]], L1 = lr[ci[1]], L2 = lr[ci[2]], L3 = lr[ci[3]];
        ce[a] = g[1]*L0 + g[3]*L1 + g[5]*L2;
        co[a] = g[0]*L0 + g[2]*L1 + g[4]*L2 + g[6]*L3;
    }
    float aee = g[1]*ce[0] + g[3]*ce[1] + g[5]*ce[2];
    float aeo = g[1]*co[0] + g[3]*co[1] + g[5]*co[2];
    float aoe = g[0]*ce[0] + g[2]*ce[1] + g[4]*ce[2] + g[6]*ce[3];
    float aoo = g[0]*co[0] + g[2]*co[1] + g[4]*co[2] + g[6]*co[3];

    size_t base = (size_t)bc * 65536 + (size_t)(2 * rh) * 256 + 2 * ch;
    float2 xe = *(const float2*)(x + base);
    float2 xo = *(const float2*)(x + base + 256);

    float* xsb = xs + (size_t)bc * 65536;
    int re = 2 * rh, ro = 2 * rh + 1;
    int ce0 = (2 * ch - re + 2) & 255;
    int co0 = (2 * ch - ro + 2) & 255;
    *(float2*)(xsb + re * 256 + ce0) = make_float2(xe.x - aee, xe.y - aeo);
    float* rowo = xsb + ro * 256;
    rowo[co0]             = xo.x - aoe;
    rowo[(co0 + 1) & 255] = xo.y - aoo;
}

// ---------------------------------------------------------------------------
// K34 fused: block = (bc, yidx), 1024 threads, 128KB LDS.
// Stage A (K3): y[r][w] = sum_{i,j} fy[i,j] xs-sheared read (col window
//   row-independent, aligned float4). Thread (wb,rg): w=4wb..+3, r=8rg..+7;
//   21 input rows, 84 b128 loads, ~2058 FMA; writes y to LDS [128][256].
// Stage B (K4): out[2yidx+{0,1}, hh, cc] = sum fT[i,j] y[(hh+2cc+i-3)%128,
//   (2cc+j-3)%256] from LDS. Thread (cc,lh): hh=16lh+m; sliding 22-row
//   window, T[p]=y[row][(2cc-4+p)&255], col 2cc-3+j -> p=j+1.
// ---------------------------------------------------------------------------
__global__ __launch_bounds__(1024) void k34_fused(
    const float* __restrict__ xs, const float* __restrict__ f0,
    const float* __restrict__ f1, float* __restrict__ out_hi)
{
    __shared__ float ylds[128 * 256];   // 128 KiB
    int t = threadIdx.x;
    int yidx = blockIdx.x & 1;
    int bc   = blockIdx.x >> 1;
    const float* xsb = xs + (size_t)bc * 65536;
    const float* fy = yidx ? f1 : f0;

    // ---- Stage A ----
    {
        int wb = t & 63;          // w = 4wb..4wb+3
        int rg = t >> 6;          // 0..15
        int r0 = rg * 8;
        int c0 = (4 * wb - 4) & 255;

        float acc[8][4];
        #pragma unroll
        for (int lr = 0; lr < 8; ++lr)
            #pragma unroll
            for (int d = 0; d < 4; ++d) acc[lr][d] = 0.f;

        int base = 2 * r0 - 3;    // first input row; 21 rows total
        #pragma unroll
        for (int ro = 0; ro < 21; ++ro) {
            int row = (base + ro + 256) & 255;
            const float* rp = xsb + row * 256;
            float C[16];
            #pragma unroll
            for (int k = 0; k < 4; ++k) {
                float4 v = *(const float4*)(rp + ((c0 + 4 * k) & 255));
                C[4*k] = v.x; C[4*k+1] = v.y; C[4*k+2] = v.z; C[4*k+3] = v.w;
            }
            #pragma unroll
            for (int lr = 0; lr < 8; ++lr) {
                int i = ro - 2 * lr;
                if (i >= 0 && i <= 6) {
                    #pragma unroll
                    for (int j = 0; j < 7; ++j) {
                        float w0 = fy[i * 7 + j];
                        int mb = j - i + 6;
                        #pragma unroll
                        for (int d = 0; d < 4; ++d)
                            acc[lr][d] += w0 * C[d + mb];
                    }
                }
            }
        }
        #pragma unroll
        for (int lr = 0; lr < 8; ++lr) {
            *(float4*)(&ylds[(r0 + lr) * 256 + 4 * wb]) =
                make_float4(acc[lr][0], acc[lr][1], acc[lr][2], acc[lr][3]);
        }
    }
    __syncthreads();

    // ---- Stage B ----
    {
        int cc = t & 127;
        int lh = t >> 7;                 // hh = 16*lh + m
        int rbase = (16 * lh + 2 * cc - 3 + 128) & 127;
        int cb64 = (2 * cc - 4) & 255;   // even base; 4 b64 cover p=0..7

        float s0[16], s1[16];
        #pragma unroll
        for (int m = 0; m < 16; ++m) { s0[m] = 0.f; s1[m] = 0.f; }

        #pragma unroll
        for (int RR = 0; RR < 22; ++RR) {
            const float* tr = &ylds[((rbase + RR) & 127) * 256];
            float T[8];
            #pragma unroll
            for (int k = 0; k < 4; ++k) {
                float2 u = *(const float2*)(tr + ((cb64 + 2 * k) & 255));
                T[2*k] = u.x; T[2*k+1] = u.y;
            }
            #pragma unroll
            for (int m = 0; m < 16; ++m) {
                int i = RR - m;
                if (i >= 0 && i <= 6) {
                    #pragma unroll
                    for (int j = 0; j < 7; ++j) {
                        s0[m] += f0[j * 7 + i] * T[j + 1];   // f0.T
                        s1[m] += f1[j * 7 + i] * T[j + 1];   // f1.T
                    }
                }
            }
        }
        #pragma unroll
        for (int m = 0; m < 16; ++m) {
            int hh = 16 * lh + m;
            size_t o = (size_t)bc * 65536 + (size_t)(2 * yidx) * 16384
                     + (size_t)hh * 128 + cc;
            out_hi[o]         = s0[m];
            out_hi[o + 16384] = s1[m];
        }
    }
}

// ---------------------------------------------------------------------------
extern "C" void kernel_launch(void* const* d_in, const int* in_sizes, int n_in,
                              void* d_out, int out_size, void* d_ws, size_t ws_size,
                              hipStream_t stream)
{
    const float* x  = (const float*)d_in[0];
    const float* h  = (const float*)d_in[1];
    const float* g  = (const float*)d_in[2];
    const float* f0 = (const float*)d_in[3];
    const float* f1 = (const float*)d_in[4];

    float* out   = (float*)d_out;
    float* xlo   = out;                 // 768*16384 floats
    float* hireg = out + 12582912;      // 768*65536: final subbands
    float* xsbuf = (float*)d_ws;        // sheared xhi, 768*65536 floats

    k1_lowpass<<<12288, 256, 0, stream>>>(x, h, xlo);
    k2_highpass<<<49152, 256, 0, stream>>>(x, g, xlo, xsbuf);
    k34_fused<<<1536, 1024, 0, stream>>>(xsbuf, f0, f1, hireg);
}